// Round 8
// baseline (780.521 us; speedup 1.0000x reference)
//
#include <hip/hip_runtime.h>
#include <hip/hip_bf16.h>
#include <math.h>

// Problem constants
#define B_ 32
#define D_ 192
#define DEPTH_ 4
#define DI_ 384
#define DS_ 16
#define DC_ 4
#define P_ 16
#define IMG_ 224
#define N_ 196
#define L_ 197

// scan chunking
#define NCH 16
#define CHL 13   // 16*13 = 208 >= 197

typedef short s16x8 __attribute__((ext_vector_type(8)));
typedef float f32x16 __attribute__((ext_vector_type(16)));

__device__ __forceinline__ float sigmoidf_(float x) { return 1.f / (1.f + expf(-x)); }
__device__ __forceinline__ float bf2f(short s) {
  unsigned int u = ((unsigned int)(unsigned short)s) << 16;
  return __uint_as_float(u);
}
__device__ __forceinline__ short f2bf(float f) {
  __hip_bfloat16 h = __float2bfloat16(f);
  return *(short*)&h;
}

// ---------------- merged im2col + prep ----------------
// blocks [0,18816): im2col x -> A bf16 (6272 x 768)
// blocks [18816, 23352): weight casts + wx pad + cls row of t + Aneg
__global__ __launch_bounds__(256) void k_prep_im2col(
    const float* __restrict__ x, __hip_bfloat16* __restrict__ A,
    const float* __restrict__ patch_w, const float* __restrict__ w_in,
    const float* __restrict__ w_out, const float* __restrict__ w_x,
    const float* __restrict__ cls_tok, const float* __restrict__ pos,
    const float* __restrict__ A_log,
    __hip_bfloat16* __restrict__ pw, __hip_bfloat16* __restrict__ win,
    __hip_bfloat16* __restrict__ wout, __hip_bfloat16* __restrict__ wx,
    float* __restrict__ t, float* __restrict__ Aneg) {
  if (blockIdx.x < 18816) {
    int idx = blockIdx.x * 256 + threadIdx.x;  // 6272*768 exact
    int tok = idx / 768, f = idx - tok * 768;
    int b = tok / 196, p = tok - b * 196;
    int h = p / 14, w = p - h * 14;
    int c = f >> 8, i = (f >> 4) & 15, j = f & 15;
    float v = x[(((size_t)(b * 3 + c) * 224 + h * 16 + i) * 224 + w * 16 + j)];
    A[idx] = __float2bfloat16(v);
    return;
  }
  int idx = (blockIdx.x - 18816) * 256 + threadIdx.x;  // 1,161,216 exact
  if (idx < 147456) { pw[idx] = __float2bfloat16(patch_w[idx]); return; }
  idx -= 147456;
  if (idx < 589824) { win[idx] = __float2bfloat16(w_in[idx]); return; }
  idx -= 589824;
  if (idx < 294912) { wout[idx] = __float2bfloat16(w_out[idx]); return; }
  idx -= 294912;
  if (idx < 98304) {
    int li = idx / 24576;
    int r = (idx / 384) & 63;
    int c = idx % 384;
    wx[idx] = (r < 33) ? __float2bfloat16(w_x[(li * 33 + r) * 384 + c]) : __float2bfloat16(0.f);
    return;
  }
  idx -= 98304;
  if (idx < 6144) {
    int b = idx / 192, d = idx % 192;
    t[(size_t)b * L_ * D_ + d] = cls_tok[d] + pos[d];
    return;
  }
  idx -= 6144;
  Aneg[idx] = -expf(A_log[idx]);  // 24576
}

// ---------------- patch GEMM (M64 x N192, K=768) + bias/pos + t write + LN(layer0) ----------------
// block covers t-rows m0..m0+63 (token space incl. cls; cls rows use zero A rows,
// keep prep-written t). Epilogue: t = acc + pb + pos (patch rows), then LN -> xln.
__global__ __launch_bounds__(256) void k_patch_ln(const short* __restrict__ A,
                                                  const short* __restrict__ pw,
                                                  const float* __restrict__ pb,
                                                  const float* __restrict__ pos,
                                                  float* __restrict__ t,
                                                  const float* __restrict__ g,
                                                  const float* __restrict__ bb,
                                                  __hip_bfloat16* __restrict__ xln) {
  __shared__ __align__(16) char smem[53248];
  short* Als = (short*)smem;              // 64*104
  short* Bls = Als + 64 * 104;            // 192*104
  float* ts = (float*)smem;               // 64*193 fp32 (49408 B) - reused after MFMA
  int m0 = blockIdx.x * 64;
  int tid = threadIdx.x;
  int lane = tid & 63, wid = tid >> 6;
  int mw = (wid & 1) * 32, nw = (wid >> 1) * 96;
  int l31 = lane & 31, lh = lane >> 5;
  f32x16 acc[3];
#pragma unroll
  for (int j = 0; j < 3; j++)
#pragma unroll
    for (int i = 0; i < 16; i++) acc[j][i] = 0.f;
  for (int kc = 0; kc < 768; kc += 96) {
    __syncthreads();
#pragma unroll
    for (int i = 0; i < 3; i++) {
      int seg = tid + i * 256;  // 768: 64 rows x 12
      int r = seg / 12, s = seg - r * 12;
      int tok = m0 + r;
      int b = tok / 197, l = tok - b * 197;
      s16x8 v = {0, 0, 0, 0, 0, 0, 0, 0};
      if (tok < 6304 && l > 0)
        v = *(const s16x8*)(A + ((size_t)(b * 196 + l - 1)) * 768 + kc + s * 8);
      *(s16x8*)(Als + r * 104 + s * 8) = v;
    }
#pragma unroll
    for (int i = 0; i < 9; i++) {
      int seg = tid + i * 256;  // 2304: 192 rows x 12
      int r = seg / 12, s = seg - r * 12;
      *(s16x8*)(Bls + r * 104 + s * 8) = *(const s16x8*)(pw + (size_t)r * 768 + kc + s * 8);
    }
    __syncthreads();
#pragma unroll
    for (int ks = 0; ks < 6; ks++) {
      s16x8 af = *(const s16x8*)(Als + (mw + l31) * 104 + ks * 16 + lh * 8);
#pragma unroll
      for (int j = 0; j < 3; j++) {
        s16x8 bf = *(const s16x8*)(Bls + (nw + j * 32 + l31) * 104 + ks * 16 + lh * 8);
        acc[j] = __builtin_amdgcn_mfma_f32_32x32x16_bf16(af, bf, acc[j], 0, 0, 0);
      }
    }
  }
  __syncthreads();
#pragma unroll
  for (int j = 0; j < 3; j++) {
    int gnl = nw + j * 32 + l31;
#pragma unroll
    for (int i = 0; i < 16; i++) {
      int rowt = mw + (i & 3) + 8 * (i >> 2) + 4 * lh;
      ts[rowt * 193 + gnl] = acc[j][i];
    }
  }
  __syncthreads();
  // epilogue: 4 threads per row
  int r = tid >> 2, part = tid & 3;
  int tok = m0 + r;
  int l = tok % 197;
  bool valid = tok < 6304;
  float* trow = t + (size_t)tok * 192;
  float s = 0.f, q = 0.f;
  for (int jj = 0; jj < 48; jj++) {
    int col = part * 48 + jj;
    float v;
    if (l == 0) {
      v = valid ? trow[col] : 0.f;
    } else {
      v = ts[r * 193 + col] + pb[col] + pos[(size_t)l * 192 + col];
      if (valid) trow[col] = v;
    }
    ts[r * 193 + col] = v;
    s += v; q += v * v;
  }
  s += __shfl_xor(s, 1, 4); s += __shfl_xor(s, 2, 4);
  q += __shfl_xor(q, 1, 4); q += __shfl_xor(q, 2, 4);
  float m = s * (1.f / 192.f);
  float rinv = rsqrtf(q * (1.f / 192.f) - m * m + 1e-5f);
  if (valid) {
    __hip_bfloat16* xrow = xln + (size_t)tok * 192;
    for (int jj = 0; jj < 48; jj++) {
      int col = part * 48 + jj;
      float v = ts[r * 193 + col];
      xrow[col] = __float2bfloat16((v - m) * rinv * g[col] + bb[col]);
    }
  }
}

// ---------------- xz = xln @ w_in^T (M64 x N64 tile, K=192), bf16 out ----------------
__global__ __launch_bounds__(256) void k_gemm_in(const short* __restrict__ A,
                                                 const short* __restrict__ Wb,
                                                 __hip_bfloat16* __restrict__ C) {
  constexpr int STR = 104;
  __shared__ __align__(16) short Als[64 * STR];
  __shared__ __align__(16) short Bls[64 * STR];
  int m0 = blockIdx.x * 64, n0 = blockIdx.y * 64;
  int tid = threadIdx.x;
  int lane = tid & 63, wid = tid >> 6;
  int mw = (wid & 1) * 32, nw = (wid >> 1) * 32;
  int l31 = lane & 31, lh = lane >> 5;
  f32x16 acc;
#pragma unroll
  for (int i = 0; i < 16; i++) acc[i] = 0.f;
  for (int kc = 0; kc < 192; kc += 96) {
    __syncthreads();
#pragma unroll
    for (int i = 0; i < 3; i++) {
      int seg = tid + i * 256;
      int r = seg / 12, s = seg - r * 12;
      *(s16x8*)(Als + r * STR + s * 8) =
          *(const s16x8*)(A + (size_t)(m0 + r) * 192 + kc + s * 8);
      *(s16x8*)(Bls + r * STR + s * 8) =
          *(const s16x8*)(Wb + (size_t)(n0 + r) * 192 + kc + s * 8);
    }
    __syncthreads();
#pragma unroll
    for (int ks = 0; ks < 6; ks++) {
      s16x8 af = *(const s16x8*)(Als + (mw + l31) * STR + ks * 16 + lh * 8);
      s16x8 bf = *(const s16x8*)(Bls + (nw + l31) * STR + ks * 16 + lh * 8);
      acc = __builtin_amdgcn_mfma_f32_32x32x16_bf16(af, bf, acc, 0, 0, 0);
    }
  }
  int gn = n0 + nw + l31;
#pragma unroll
  for (int i = 0; i < 16; i++) {
    int rowt = mw + (i & 3) + 8 * (i >> 2) + 4 * lh;
    int gm = m0 + rowt;
    if (gm < 6304) C[(size_t)gm * 768 + gn] = __float2bfloat16(acc[i]);
  }
}

// ---------------- fused conv + bcd GEMM ----------------
// Per K-chunk of 96: build A-tile = silu(conv(xz)) in LDS (also -> xa_bf global),
// stage wx B-tile, MFMA. Epilogue: bcd write + sz = silu(z) -> sz_bf.
__global__ __launch_bounds__(256) void k_convbcd(const __hip_bfloat16* __restrict__ xz,
                                                 const float* __restrict__ cw_,
                                                 const float* __restrict__ cb_,
                                                 const short* __restrict__ wx,
                                                 float* __restrict__ bcd,
                                                 __hip_bfloat16* __restrict__ xa_bf,
                                                 __hip_bfloat16* __restrict__ sz_bf) {
  __shared__ float xs[67 * 96];
  __shared__ __align__(16) short Als[64 * 104];
  __shared__ __align__(16) short Bls[64 * 104];
  __shared__ float cws[96 * 4];
  __shared__ float cbs[96];
  int m0 = blockIdx.x * 64;
  int tid = threadIdx.x;
  int lane = tid & 63, wid = tid >> 6;
  int mw = (wid & 1) * 32, nw = (wid >> 1) * 32;
  int l31 = lane & 31, lh = lane >> 5;
  f32x16 acc;
#pragma unroll
  for (int i = 0; i < 16; i++) acc[i] = 0.f;
  for (int kc = 0; kc < 384; kc += 96) {
    __syncthreads();
    // stage xz x-part rows m0-3..m0+63 cols kc..kc+95 as fp32 (804 segs of 8)
#pragma unroll
    for (int i = 0; i < 4; i++) {
      int seg = tid + i * 256;
      if (seg < 804) {
        int row = seg / 12, s = seg - row * 12;
        int tokp = m0 - 3 + row;
        s16x8 v = {0, 0, 0, 0, 0, 0, 0, 0};
        if (tokp >= 0 && tokp < 6304)
          v = *(const s16x8*)((const short*)xz + (size_t)tokp * 768 + kc + s * 8);
        float4 f0 = make_float4(bf2f(v[0]), bf2f(v[1]), bf2f(v[2]), bf2f(v[3]));
        float4 f1 = make_float4(bf2f(v[4]), bf2f(v[5]), bf2f(v[6]), bf2f(v[7]));
        *(float4*)(xs + row * 96 + s * 8) = f0;
        *(float4*)(xs + row * 96 + s * 8 + 4) = f1;
      }
    }
    // conv weights for this chunk
    if (tid < 96) {
      *(float4*)(cws + tid * 4) = *(const float4*)(cw_ + (kc + tid) * 4);
      cbs[tid] = cb_[kc + tid];
    }
    // B-tile: wx rows 0..63
#pragma unroll
    for (int i = 0; i < 3; i++) {
      int seg = tid + i * 256;
      int r = seg / 12, s = seg - r * 12;
      *(s16x8*)(Bls + r * 104 + s * 8) = *(const s16x8*)(wx + (size_t)r * 384 + kc + s * 8);
    }
    __syncthreads();
    // conv + silu -> Als (bf16) + xa_bf global
#pragma unroll
    for (int i = 0; i < 24; i++) {
      int idx = tid + i * 256;  // 6144
      int orow = idx / 96, c = idx - orow * 96;
      int tok = m0 + orow;
      int l = tok % 197;
      float4 cw = *(const float4*)(cws + c * 4);
      float a = fmaf(cw.w, xs[(orow + 3) * 96 + c], cbs[c]);
      if (l >= 1) a = fmaf(cw.z, xs[(orow + 2) * 96 + c], a);
      if (l >= 2) a = fmaf(cw.y, xs[(orow + 1) * 96 + c], a);
      if (l >= 3) a = fmaf(cw.x, xs[orow * 96 + c], a);
      float xav = a * sigmoidf_(a);
      short bv = f2bf(xav);
      Als[orow * 104 + c] = bv;
      if (tok < 6304) ((short*)xa_bf)[(size_t)tok * 384 + kc + c] = bv;
    }
    __syncthreads();
#pragma unroll
    for (int ks = 0; ks < 6; ks++) {
      s16x8 af = *(const s16x8*)(Als + (mw + l31) * 104 + ks * 16 + lh * 8);
      s16x8 bf = *(const s16x8*)(Bls + (nw + l31) * 104 + ks * 16 + lh * 8);
      acc = __builtin_amdgcn_mfma_f32_32x32x16_bf16(af, bf, acc, 0, 0, 0);
    }
  }
  // bcd epilogue
  int gn = nw + l31;
#pragma unroll
  for (int i = 0; i < 16; i++) {
    int rowt = mw + (i & 3) + 8 * (i >> 2) + 4 * lh;
    int gm = m0 + rowt;
    if (gm < 6304) bcd[(size_t)gm * 64 + gn] = acc[i];
  }
  // sz epilogue: z half, 64 rows x 384 cols = 3072 bf16x8 segs
#pragma unroll
  for (int i = 0; i < 12; i++) {
    int seg = tid + i * 256;
    int r = seg / 48, s = seg - r * 48;
    int tok = m0 + r;
    if (tok < 6304) {
      s16x8 zv = *(const s16x8*)((const short*)xz + (size_t)tok * 768 + 384 + s * 8);
      s16x8 ov;
#pragma unroll
      for (int e = 0; e < 8; e++) {
        float z = bf2f(zv[e]);
        ov[e] = f2bf(z * sigmoidf_(z));
      }
      *(s16x8*)((short*)sz_bf + (size_t)tok * 384 + s * 8) = ov;
    }
  }
}

// ---------------- scan phase 1: chunk-local scan, store P (prod dA) and H_local ----------------
__global__ __launch_bounds__(384) void k_scan1(const __hip_bfloat16* __restrict__ xa,
                                               const float* __restrict__ bcd,
                                               const float* __restrict__ Aneg,
                                               const float* __restrict__ w_dt,
                                               const float* __restrict__ b_dt,
                                               float* __restrict__ Pst,
                                               float* __restrict__ Hst) {
  int b = blockIdx.x >> 4, ch = blockIdx.x & 15;
  int d = threadIdx.x;
  int l0 = ch * CHL;
  int lim = min(CHL, L_ - l0);
  float Av[16];
#pragma unroll
  for (int q = 0; q < 4; q++) {
    float4 v = *(const float4*)(Aneg + d * 16 + q * 4);
    Av[q * 4] = v.x; Av[q * 4 + 1] = v.y; Av[q * 4 + 2] = v.z; Av[q * 4 + 3] = v.w;
  }
  float wdt = w_dt[d], bdt = b_dt[d];
  const __hip_bfloat16* xap = xa + ((size_t)b * L_ + l0) * DI_ + d;
  const float* bp = bcd + ((size_t)b * L_ + l0) * 64;
  float h[16], Pp[16];
#pragma unroll
  for (int n = 0; n < 16; n++) { h[n] = 0.f; Pp[n] = 1.f; }
  float xv = __bfloat162float(xap[0]);
  for (int j = 0; j < lim; j++) {
    int jn = (j + 1 < lim) ? (j + 1) : j;
    float xn = __bfloat162float(xap[(size_t)jn * DI_]);
    float dtraw = bp[j * 64 + 32];
    float Bn[16];
#pragma unroll
    for (int n = 0; n < 16; n++) Bn[n] = bp[j * 64 + n];
    float v = fmaf(dtraw, wdt, bdt);
    float dtv = (v > 20.f) ? v : __logf(1.f + __expf(v));
    float dtx = dtv * xv;
#pragma unroll
    for (int n = 0; n < 16; n++) {
      float dA = __expf(dtv * Av[n]);
      h[n] = fmaf(dA, h[n], dtx * Bn[n]);
      Pp[n] *= dA;
    }
    xv = xn;
  }
  size_t s = ((size_t)blockIdx.x * 384 + d) * 16;
#pragma unroll
  for (int q = 0; q < 4; q++) {
    *(float4*)(Pst + s + q * 4) = make_float4(Pp[q * 4], Pp[q * 4 + 1], Pp[q * 4 + 2], Pp[q * 4 + 3]);
    *(float4*)(Hst + s + q * 4) = make_float4(h[q * 4], h[q * 4 + 1], h[q * 4 + 2], h[q * 4 + 3]);
  }
}

// ---------------- scan phase 2: inline lookback + rescan + C-dot + D + silu(z) ----------------
__global__ __launch_bounds__(384) void k_scan2(const __hip_bfloat16* __restrict__ xa,
                                               const __hip_bfloat16* __restrict__ sz,
                                               const float* __restrict__ bcd,
                                               const float* __restrict__ Aneg,
                                               const float* __restrict__ D_ssm,
                                               const float* __restrict__ w_dt,
                                               const float* __restrict__ b_dt,
                                               const float* __restrict__ Pst,
                                               const float* __restrict__ Hst,
                                               __hip_bfloat16* __restrict__ y) {
  int b = blockIdx.x >> 4, ch = blockIdx.x & 15;
  int d = threadIdx.x;
  int l0 = ch * CHL;
  int lim = min(CHL, L_ - l0);
  float Av[16];
#pragma unroll
  for (int q = 0; q < 4; q++) {
    float4 v = *(const float4*)(Aneg + d * 16 + q * 4);
    Av[q * 4] = v.x; Av[q * 4 + 1] = v.y; Av[q * 4 + 2] = v.z; Av[q * 4 + 3] = v.w;
  }
  float Dv = D_ssm[d];
  float wdt = w_dt[d], bdt = b_dt[d];
  // lookback: h = combine of chunks 0..ch-1
  float h[16];
#pragma unroll
  for (int n = 0; n < 16; n++) h[n] = 0.f;
  for (int c = 0; c < ch; c++) {
    size_t o = ((size_t)(b * NCH + c) * 384 + d) * 16;
#pragma unroll
    for (int q = 0; q < 4; q++) {
      float4 P = *(const float4*)(Pst + o + q * 4);
      float4 H = *(const float4*)(Hst + o + q * 4);
      h[q * 4]     = fmaf(P.x, h[q * 4],     H.x);
      h[q * 4 + 1] = fmaf(P.y, h[q * 4 + 1], H.y);
      h[q * 4 + 2] = fmaf(P.z, h[q * 4 + 2], H.z);
      h[q * 4 + 3] = fmaf(P.w, h[q * 4 + 3], H.w);
    }
  }
  const __hip_bfloat16* xap = xa + ((size_t)b * L_ + l0) * DI_ + d;
  const __hip_bfloat16* szp = sz + ((size_t)b * L_ + l0) * DI_ + d;
  const float* bp = bcd + ((size_t)b * L_ + l0) * 64;
  __hip_bfloat16* yp = y + ((size_t)b * L_ + l0) * DI_ + d;
  float xv = __bfloat162float(xap[0]);
  float szv = __bfloat162float(szp[0]);
  for (int j = 0; j < lim; j++) {
    int jn = (j + 1 < lim) ? (j + 1) : j;
    float xn = __bfloat162float(xap[(size_t)jn * DI_]);
    float szn = __bfloat162float(szp[(size_t)jn * DI_]);
    float dtraw = bp[j * 64 + 32];
    float Bn[16], Cn[16];
#pragma unroll
    for (int n = 0; n < 16; n++) Bn[n] = bp[j * 64 + n];
#pragma unroll
    for (int n = 0; n < 16; n++) Cn[n] = bp[j * 64 + 16 + n];
    float v = fmaf(dtraw, wdt, bdt);
    float dtv = (v > 20.f) ? v : __logf(1.f + __expf(v));
    float dtx = dtv * xv;
    float acc = 0.f;
#pragma unroll
    for (int n = 0; n < 16; n++) {
      float dA = __expf(dtv * Av[n]);
      h[n] = fmaf(dA, h[n], dtx * Bn[n]);
      acc = fmaf(h[n], Cn[n], acc);
    }
    float yv = fmaf(xv, Dv, acc) * szv;
    yp[(size_t)j * DI_] = __float2bfloat16(yv);
    xv = xn; szv = szn;
  }
}

// ---------------- out GEMM (M64 x N192, K=384): t += y @ w_out^T, then LN(next layer) ----------------
template <bool DO_LN>
__global__ __launch_bounds__(256) void k_out_ln(const short* __restrict__ A,
                                                const short* __restrict__ wout,
                                                float* __restrict__ t,
                                                const float* __restrict__ g,
                                                const float* __restrict__ bb,
                                                __hip_bfloat16* __restrict__ xln) {
  __shared__ __align__(16) char smem[53248];
  short* Als = (short*)smem;
  short* Bls = Als + 64 * 104;
  float* ts = (float*)smem;
  int m0 = blockIdx.x * 64;
  int tid = threadIdx.x;
  int lane = tid & 63, wid = tid >> 6;
  int mw = (wid & 1) * 32, nw = (wid >> 1) * 96;
  int l31 = lane & 31, lh = lane >> 5;
  f32x16 acc[3];
#pragma unroll
  for (int j = 0; j < 3; j++)
#pragma unroll
    for (int i = 0; i < 16; i++) acc[j][i] = 0.f;
  for (int kc = 0; kc < 384; kc += 96) {
    __syncthreads();
#pragma unroll
    for (int i = 0; i < 3; i++) {
      int seg = tid + i * 256;
      int r = seg / 12, s = seg - r * 12;
      *(s16x8*)(Als + r * 104 + s * 8) =
          *(const s16x8*)(A + (size_t)(m0 + r) * 384 + kc + s * 8);
    }
#pragma unroll
    for (int i = 0; i < 9; i++) {
      int seg = tid + i * 256;
      int r = seg / 12, s = seg - r * 12;
      *(s16x8*)(Bls + r * 104 + s * 8) = *(const s16x8*)(wout + (size_t)r * 384 + kc + s * 8);
    }
    __syncthreads();
#pragma unroll
    for (int ks = 0; ks < 6; ks++) {
      s16x8 af = *(const s16x8*)(Als + (mw + l31) * 104 + ks * 16 + lh * 8);
#pragma unroll
      for (int j = 0; j < 3; j++) {
        s16x8 bf = *(const s16x8*)(Bls + (nw + j * 32 + l31) * 104 + ks * 16 + lh * 8);
        acc[j] = __builtin_amdgcn_mfma_f32_32x32x16_bf16(af, bf, acc[j], 0, 0, 0);
      }
    }
  }
  __syncthreads();
#pragma unroll
  for (int j = 0; j < 3; j++) {
    int gnl = nw + j * 32 + l31;
#pragma unroll
    for (int i = 0; i < 16; i++) {
      int rowt = mw + (i & 3) + 8 * (i >> 2) + 4 * lh;
      ts[rowt * 193 + gnl] = acc[j][i];
    }
  }
  __syncthreads();
  int r = tid >> 2, part = tid & 3;
  int tok = m0 + r;
  bool valid = tok < 6304;
  float* trow = t + (size_t)tok * 192;
  float s = 0.f, q = 0.f;
  for (int jj = 0; jj < 48; jj++) {
    int col = part * 48 + jj;
    float v = ts[r * 193 + col];
    if (valid) {
      v += trow[col];
      trow[col] = v;
    }
    ts[r * 193 + col] = v;
    s += v; q += v * v;
  }
  if (DO_LN) {
    s += __shfl_xor(s, 1, 4); s += __shfl_xor(s, 2, 4);
    q += __shfl_xor(q, 1, 4); q += __shfl_xor(q, 2, 4);
    float m = s * (1.f / 192.f);
    float rinv = rsqrtf(q * (1.f / 192.f) - m * m + 1e-5f);
    if (valid) {
      __hip_bfloat16* xrow = xln + (size_t)tok * 192;
      for (int jj = 0; jj < 48; jj++) {
        int col = part * 48 + jj;
        float v = ts[r * 193 + col];
        xrow[col] = __float2bfloat16((v - m) * rinv * g[col] + bb[col]);
      }
    }
  }
}

// ---------------- final LN(token 0) + cls head + reg head ----------------
__global__ __launch_bounds__(192) void k_head(const float* __restrict__ t,
                                              const float* __restrict__ fn_g,
                                              const float* __restrict__ fn_b,
                                              const float* __restrict__ cls_w,
                                              const float* __restrict__ cls_b,
                                              const float* __restrict__ rw1,
                                              const float* __restrict__ rb1,
                                              const float* __restrict__ rw2,
                                              const float* __restrict__ rb2,
                                              float* __restrict__ out) {
  __shared__ float red[8];
  __shared__ float stats[2];
  __shared__ float feat_s[192];
  __shared__ float h_s[96];
  int b = blockIdx.x, tid = threadIdx.x;
  float x = t[(size_t)b * L_ * D_ + tid];
  float s = x, q = x * x;
#pragma unroll
  for (int off = 1; off < 64; off <<= 1) {
    s += __shfl_xor(s, off, 64);
    q += __shfl_xor(q, off, 64);
  }
  int w = tid >> 6;
  if ((tid & 63) == 0) { red[w] = s; red[4 + w] = q; }
  __syncthreads();
  if (tid == 0) {
    float ss = red[0] + red[1] + red[2];
    float qq = red[4] + red[5] + red[6];
    float m = ss * (1.f / 192.f);
    stats[0] = m;
    stats[1] = rsqrtf(qq * (1.f / 192.f) - m * m + 1e-5f);
  }
  __syncthreads();
  float fv = (x - stats[0]) * stats[1] * fn_g[tid] + fn_b[tid];
  feat_s[tid] = fv;
  __syncthreads();
  if (tid < 96) {
    float a = rb1[tid];
    const float* wr = rw1 + (size_t)tid * 192;
    for (int k = 0; k < 192; k++) a = fmaf(feat_s[k], wr[k], a);
    h_s[tid] = 0.5f * a * (1.f + erff(a * 0.70710678118654752f));
  } else if (tid < 98) {
    int c = tid - 96;
    float a = cls_b[c];
    const float* wr = cls_w + (size_t)c * 192;
    for (int k = 0; k < 192; k++) a = fmaf(feat_s[k], wr[k], a);
    out[b * 2 + c] = a;
  }
  __syncthreads();
  if (tid == 0) {
    float a = rb2[0];
    for (int j = 0; j < 96; j++) a = fmaf(h_s[j], rw2[j], a);
    out[64 + b] = a;
  }
}

extern "C" void kernel_launch(void* const* d_in, const int* in_sizes, int n_in,
                              void* d_out, int out_size, void* d_ws, size_t ws_size,
                              hipStream_t stream) {
  const float* x       = (const float*)d_in[0];
  const float* patch_w = (const float*)d_in[1];
  const float* patch_b = (const float*)d_in[2];
  const float* cls_tok = (const float*)d_in[3];
  const float* pos     = (const float*)d_in[4];
  const float* ln_g    = (const float*)d_in[5];
  const float* ln_b    = (const float*)d_in[6];
  const float* w_in    = (const float*)d_in[7];
  const float* conv_w  = (const float*)d_in[8];
  const float* conv_b  = (const float*)d_in[9];
  const float* w_x     = (const float*)d_in[10];
  const float* w_dt    = (const float*)d_in[11];
  const float* b_dt    = (const float*)d_in[12];
  const float* A_log   = (const float*)d_in[13];
  const float* D_ssm   = (const float*)d_in[14];
  const float* w_out   = (const float*)d_in[15];
  const float* fn_g    = (const float*)d_in[16];
  const float* fn_b    = (const float*)d_in[17];
  const float* cls_w   = (const float*)d_in[18];
  const float* cls_b   = (const float*)d_in[19];
  const float* reg_w1  = (const float*)d_in[20];
  const float* reg_b1  = (const float*)d_in[21];
  const float* reg_w2  = (const float*)d_in[22];
  const float* reg_b2  = (const float*)d_in[23];
  float* out = (float*)d_out;

  float* ws = (float*)d_ws;
  // fp32 region
  float* t_buf = ws;                         // 1,210,368
  float* bcd   = t_buf + 1210368;            // 6336*64 = 405,504
  float* Pst   = bcd + 405504;               // 32*16*6144 = 3,145,728
  float* Hst   = Pst + 3145728;              // 3,145,728
  float* Aneg  = Hst + 3145728;              // 24,576
  // bf16 region
  __hip_bfloat16* xz_bf  = (__hip_bfloat16*)(Aneg + 24576);  // 6304*768 = 4,841,472
  __hip_bfloat16* Abuf   = xz_bf;            // alias: im2col output dead after patch gemm
  __hip_bfloat16* xa_bf  = xz_bf + 4841472;  // 6336*384 = 2,433,024
  __hip_bfloat16* sz_bf  = xa_bf + 2433024;  // 2,433,024
  __hip_bfloat16* xln_bf = sz_bf + 2433024;  // 6336*192 = 1,216,512
  __hip_bfloat16* y_bf   = xln_bf + 1216512; // 2,433,024
  __hip_bfloat16* pw_bf  = y_bf + 2433024;   // 147,456
  __hip_bfloat16* win_bf = pw_bf + 147456;   // 589,824
  __hip_bfloat16* wout_bf = win_bf + 589824; // 294,912
  __hip_bfloat16* wx_bf  = wout_bf + 294912; // 98,304

  k_prep_im2col<<<23352, 256, 0, stream>>>(x, Abuf, patch_w, w_in, w_out, w_x,
                                           cls_tok, pos, A_log, pw_bf, win_bf,
                                           wout_bf, wx_bf, t_buf, Aneg);
  k_patch_ln<<<99, 256, 0, stream>>>((const short*)Abuf, (const short*)pw_bf,
                                     patch_b, pos, t_buf, ln_g, ln_b, xln_bf);

  for (int i = 0; i < DEPTH_; i++) {
    k_gemm_in<<<dim3(99, 12), 256, 0, stream>>>(
        (const short*)xln_bf, (const short*)(win_bf + (size_t)i * 147456), xz_bf);
    k_convbcd<<<99, 256, 0, stream>>>(xz_bf, conv_w + i * DI_ * DC_, conv_b + i * DI_,
                                      (const short*)(wx_bf + (size_t)i * 24576),
                                      bcd, xa_bf, sz_bf);
    k_scan1<<<B_ * NCH, 384, 0, stream>>>(xa_bf, bcd, Aneg + i * 6144,
                                          w_dt + i * DI_, b_dt + i * DI_, Pst, Hst);
    k_scan2<<<B_ * NCH, 384, 0, stream>>>(xa_bf, sz_bf, bcd, Aneg + i * 6144,
                                          D_ssm + i * DI_, w_dt + i * DI_, b_dt + i * DI_,
                                          Pst, Hst, y_bf);
    if (i < DEPTH_ - 1) {
      k_out_ln<true><<<99, 256, 0, stream>>>(
          (const short*)y_bf, (const short*)(wout_bf + (size_t)i * 73728), t_buf,
          ln_g + (i + 1) * D_, ln_b + (i + 1) * D_, xln_bf);
    } else {
      k_out_ln<false><<<99, 256, 0, stream>>>(
          (const short*)y_bf, (const short*)(wout_bf + (size_t)i * 73728), t_buf,
          nullptr, nullptr, nullptr);
    }
  }
  k_head<<<32, 192, 0, stream>>>(t_buf, fn_g, fn_b, cls_w, cls_b, reg_w1, reg_b1,
                                 reg_w2, reg_b2, out);
}

// Round 9
// 564.826 us; speedup vs baseline: 1.3819x; 1.3819x over previous
//
#include <hip/hip_runtime.h>
#include <hip/hip_bf16.h>
#include <math.h>

// Problem constants
#define B_ 32
#define D_ 192
#define DEPTH_ 4
#define DI_ 384
#define DS_ 16
#define DC_ 4
#define P_ 16
#define IMG_ 224
#define N_ 196
#define L_ 197

// scan chunking
#define NCH 16
#define CHL 13   // 16*13 = 208 >= 197

typedef short s16x8 __attribute__((ext_vector_type(8)));
typedef short s16x4 __attribute__((ext_vector_type(4)));
typedef float f32x16 __attribute__((ext_vector_type(16)));

__device__ __forceinline__ float sigmoidf_(float x) { return 1.f / (1.f + expf(-x)); }
__device__ __forceinline__ short f2bf(float f) {
  __hip_bfloat16 h = __float2bfloat16(f);
  return *(short*)&h;
}

// ---------------- merged im2col + prep ----------------
__global__ __launch_bounds__(256) void k_prep_im2col(
    const float* __restrict__ x, __hip_bfloat16* __restrict__ A,
    const float* __restrict__ patch_w, const float* __restrict__ w_in,
    const float* __restrict__ w_out, const float* __restrict__ w_x,
    const float* __restrict__ cls_tok, const float* __restrict__ pos,
    const float* __restrict__ A_log,
    __hip_bfloat16* __restrict__ pw, __hip_bfloat16* __restrict__ win,
    __hip_bfloat16* __restrict__ wout, __hip_bfloat16* __restrict__ wx,
    float* __restrict__ t, float* __restrict__ Aneg) {
  if (blockIdx.x < 18816) {
    int idx = blockIdx.x * 256 + threadIdx.x;  // 6272*768 exact
    int tok = idx / 768, f = idx - tok * 768;
    int b = tok / 196, p = tok - b * 196;
    int h = p / 14, w = p - h * 14;
    int c = f >> 8, i = (f >> 4) & 15, j = f & 15;
    float v = x[(((size_t)(b * 3 + c) * 224 + h * 16 + i) * 224 + w * 16 + j)];
    A[idx] = __float2bfloat16(v);
    return;
  }
  int idx = (blockIdx.x - 18816) * 256 + threadIdx.x;  // 1,161,216 exact
  if (idx < 147456) { pw[idx] = __float2bfloat16(patch_w[idx]); return; }
  idx -= 147456;
  if (idx < 589824) { win[idx] = __float2bfloat16(w_in[idx]); return; }
  idx -= 589824;
  if (idx < 294912) { wout[idx] = __float2bfloat16(w_out[idx]); return; }
  idx -= 294912;
  if (idx < 98304) {
    int li = idx / 24576;
    int r = (idx / 384) & 63;
    int c = idx % 384;
    wx[idx] = (r < 33) ? __float2bfloat16(w_x[(li * 33 + r) * 384 + c]) : __float2bfloat16(0.f);
    return;
  }
  idx -= 98304;
  if (idx < 6144) {
    int b = idx / 192, d = idx % 192;
    t[(size_t)b * L_ * D_ + d] = cls_tok[d] + pos[d];
    return;
  }
  idx -= 6144;
  Aneg[idx] = -expf(A_log[idx]);  // 24576
}

// ---------------- generic bf16 MFMA GEMM (modes 2,3) ----------------
// MODE 2: patch epilogue: t[(b*197+1+p)*192+n] = acc + bias[n] + pos[(1+p)*192+n]
// MODE 3: C fp32 (stride 64) = acc              (bcd = xa @ w_x_pad^T)
template <int KTOT, int MODE>
__global__ __launch_bounds__(256) void k_gemm_mfma(const short* __restrict__ A,
                                                   const short* __restrict__ Wb,
                                                   float* __restrict__ C,
                                                   const float* __restrict__ bias,
                                                   const float* __restrict__ pos,
                                                   int M) {
  constexpr int KC = 96;
  constexpr int STR = 104;
  __shared__ __align__(16) short Als[64 * STR];
  __shared__ __align__(16) short Bls[64 * STR];
  int m0 = blockIdx.x * 64, n0 = blockIdx.y * 64;
  int tid = threadIdx.x;
  int lane = tid & 63, wid = tid >> 6;
  int mw = (wid & 1) * 32, nw = (wid >> 1) * 32;
  int l31 = lane & 31, lh = lane >> 5;
  f32x16 acc;
#pragma unroll
  for (int i = 0; i < 16; i++) acc[i] = 0.f;
  for (int kc = 0; kc < KTOT; kc += KC) {
    __syncthreads();
#pragma unroll
    for (int i = 0; i < 3; i++) {
      int seg = tid + i * 256;
      int r = seg / 12, s = seg - r * 12;
      *(s16x8*)(Als + r * STR + s * 8) =
          *(const s16x8*)(A + (size_t)(m0 + r) * KTOT + kc + s * 8);
      *(s16x8*)(Bls + r * STR + s * 8) =
          *(const s16x8*)(Wb + (size_t)(n0 + r) * KTOT + kc + s * 8);
    }
    __syncthreads();
#pragma unroll
    for (int ks = 0; ks < KC / 16; ks++) {
      s16x8 af = *(const s16x8*)(Als + (mw + l31) * STR + ks * 16 + lh * 8);
      s16x8 bf = *(const s16x8*)(Bls + (nw + l31) * STR + ks * 16 + lh * 8);
      acc = __builtin_amdgcn_mfma_f32_32x32x16_bf16(af, bf, acc, 0, 0, 0);
    }
  }
  int gn = n0 + nw + l31;
#pragma unroll
  for (int i = 0; i < 16; i++) {
    int rowt = mw + (i & 3) + 8 * (i >> 2) + 4 * lh;
    int gm = m0 + rowt;
    float v = acc[i];
    if (MODE == 3) {
      if (gm < M) C[(size_t)gm * 64 + gn] = v;
    } else {
      int b = gm / 196, p = gm - b * 196;
      C[((size_t)b * 197 + 1 + p) * 192 + gn] =
          v + bias[gn] + pos[(size_t)(1 + p) * 192 + gn];
    }
  }
}

// ---------------- fused LN + xz GEMM: xz = LN(t) @ w_in^T ----------------
// grid (99,12). LN computed per block in registers (4 thr/row, 12 float4 each),
// written as bf16 straight into the A-tile LDS. Full K=192 resident -> 1 barrier.
__global__ __launch_bounds__(256) void k_gemm_in_ln(const float* __restrict__ t,
                                                    const float* __restrict__ g,
                                                    const float* __restrict__ bb,
                                                    const short* __restrict__ Wb,
                                                    __hip_bfloat16* __restrict__ xz) {
  __shared__ __align__(16) short Als[64 * 200];
  __shared__ __align__(16) short Bls[64 * 200];
  int m0 = blockIdx.x * 64, n0 = blockIdx.y * 64;
  int tid = threadIdx.x;
  // stage B: 64 rows x 192 = 1536 segs of 8
#pragma unroll
  for (int i = 0; i < 6; i++) {
    int seg = tid + i * 256;
    int r = seg / 24, s = seg - r * 24;
    *(s16x8*)(Bls + r * 200 + s * 8) =
        *(const s16x8*)(Wb + (size_t)(n0 + r) * 192 + s * 8);
  }
  // LN: 4 threads per row, 48 cols each
  {
    int r = tid >> 2, part = tid & 3;
    int tok = m0 + r;
    int tokc = (tok < 6304) ? tok : 6303;
    const float* trow = t + (size_t)tokc * 192 + part * 48;
    float4 v[12];
    float s = 0.f, q = 0.f;
#pragma unroll
    for (int i = 0; i < 12; i++) {
      v[i] = *(const float4*)(trow + i * 4);
      s += v[i].x + v[i].y + v[i].z + v[i].w;
      q += v[i].x * v[i].x + v[i].y * v[i].y + v[i].z * v[i].z + v[i].w * v[i].w;
    }
    s += __shfl_xor(s, 1, 4); s += __shfl_xor(s, 2, 4);
    q += __shfl_xor(q, 1, 4); q += __shfl_xor(q, 2, 4);
    float m = s * (1.f / 192.f);
    float rinv = rsqrtf(q * (1.f / 192.f) - m * m + 1e-5f);
#pragma unroll
    for (int i = 0; i < 12; i++) {
      int c0 = part * 48 + i * 4;
      s16x4 o;
      o[0] = f2bf((v[i].x - m) * rinv * g[c0]     + bb[c0]);
      o[1] = f2bf((v[i].y - m) * rinv * g[c0 + 1] + bb[c0 + 1]);
      o[2] = f2bf((v[i].z - m) * rinv * g[c0 + 2] + bb[c0 + 2]);
      o[3] = f2bf((v[i].w - m) * rinv * g[c0 + 3] + bb[c0 + 3]);
      *(s16x4*)(Als + r * 200 + c0) = o;
    }
  }
  __syncthreads();
  int lane = tid & 63, wid = tid >> 6;
  int mw = (wid & 1) * 32, nw = (wid >> 1) * 32;
  int l31 = lane & 31, lh = lane >> 5;
  f32x16 acc;
#pragma unroll
  for (int i = 0; i < 16; i++) acc[i] = 0.f;
#pragma unroll
  for (int ks = 0; ks < 12; ks++) {
    s16x8 af = *(const s16x8*)(Als + (mw + l31) * 200 + ks * 16 + lh * 8);
    s16x8 bf = *(const s16x8*)(Bls + (nw + l31) * 200 + ks * 16 + lh * 8);
    acc = __builtin_amdgcn_mfma_f32_32x32x16_bf16(af, bf, acc, 0, 0, 0);
  }
  int gn = n0 + nw + l31;
#pragma unroll
  for (int i = 0; i < 16; i++) {
    int rowt = mw + (i & 3) + 8 * (i >> 2) + 4 * lh;
    int gm = m0 + rowt;
    if (gm < 6304) xz[(size_t)gm * 768 + gn] = __float2bfloat16(acc[i]);
  }
}

// ---------------- t += y @ w_out^T (MODE 1 style, grid (99,3)) ----------------
__global__ __launch_bounds__(256) void k_gemm_out(const short* __restrict__ A,
                                                  const short* __restrict__ Wb,
                                                  float* __restrict__ C) {
  constexpr int STR = 104;
  __shared__ __align__(16) short Als[64 * STR];
  __shared__ __align__(16) short Bls[64 * STR];
  int m0 = blockIdx.x * 64, n0 = blockIdx.y * 64;
  int tid = threadIdx.x;
  int lane = tid & 63, wid = tid >> 6;
  int mw = (wid & 1) * 32, nw = (wid >> 1) * 32;
  int l31 = lane & 31, lh = lane >> 5;
  f32x16 acc;
#pragma unroll
  for (int i = 0; i < 16; i++) acc[i] = 0.f;
  for (int kc = 0; kc < 384; kc += 96) {
    __syncthreads();
#pragma unroll
    for (int i = 0; i < 3; i++) {
      int seg = tid + i * 256;
      int r = seg / 12, s = seg - r * 12;
      *(s16x8*)(Als + r * STR + s * 8) =
          *(const s16x8*)(A + (size_t)(m0 + r) * 384 + kc + s * 8);
      *(s16x8*)(Bls + r * STR + s * 8) =
          *(const s16x8*)(Wb + (size_t)(n0 + r) * 384 + kc + s * 8);
    }
    __syncthreads();
#pragma unroll
    for (int ks = 0; ks < 6; ks++) {
      s16x8 af = *(const s16x8*)(Als + (mw + l31) * STR + ks * 16 + lh * 8);
      s16x8 bf = *(const s16x8*)(Bls + (nw + l31) * STR + ks * 16 + lh * 8);
      acc = __builtin_amdgcn_mfma_f32_32x32x16_bf16(af, bf, acc, 0, 0, 0);
    }
  }
  int gn = n0 + nw + l31;
#pragma unroll
  for (int i = 0; i < 16; i++) {
    int rowt = mw + (i & 3) + 8 * (i >> 2) + 4 * lh;
    int gm = m0 + rowt;
    if (gm < 6304) C[(size_t)gm * 192 + gn] += acc[i];
  }
}

// ---------------- causal depthwise conv + silu: 8 tokens/block, LDS window ----------------
__global__ __launch_bounds__(384) void k_conv(const __hip_bfloat16* __restrict__ xz,
                                              const float* __restrict__ cw_,
                                              const float* __restrict__ cb,
                                              __hip_bfloat16* __restrict__ xa_bf,
                                              __hip_bfloat16* __restrict__ sz_bf) {
  __shared__ float xs[11][384];
  int r0 = blockIdx.x * 8;  // 788 blocks * 8 = 6304
  int d = threadIdx.x;
#pragma unroll
  for (int row = 0; row < 11; row++) {
    int gr = r0 - 3 + row;
    if (gr >= 0) xs[row][d] = __bfloat162float(xz[(size_t)gr * 768 + d]);
  }
  __syncthreads();
  float4 cw = *(const float4*)(cw_ + d * 4);
  float cbv = cb[d];
#pragma unroll
  for (int tk = 0; tk < 8; tk++) {
    int tok = r0 + tk;
    int l = tok % L_;
    float acc = fmaf(cw.w, xs[tk + 3][d], cbv);
    if (l >= 1) acc = fmaf(cw.z, xs[tk + 2][d], acc);
    if (l >= 2) acc = fmaf(cw.y, xs[tk + 1][d], acc);
    if (l >= 3) acc = fmaf(cw.x, xs[tk][d], acc);
    float xav = acc * sigmoidf_(acc);
    xa_bf[(size_t)tok * DI_ + d] = __float2bfloat16(xav);
    float z = __bfloat162float(xz[(size_t)tok * 768 + 384 + d]);
    sz_bf[(size_t)tok * DI_ + d] = __float2bfloat16(z * sigmoidf_(z));
  }
}

// ---------------- scan phase 1: chunk-local scan, store P (prod dA) and H_local ----------------
__global__ __launch_bounds__(384) void k_scan1(const __hip_bfloat16* __restrict__ xa,
                                               const float* __restrict__ bcd,
                                               const float* __restrict__ Aneg,
                                               const float* __restrict__ w_dt,
                                               const float* __restrict__ b_dt,
                                               float* __restrict__ Pst,
                                               float* __restrict__ Hst) {
  int b = blockIdx.x >> 4, ch = blockIdx.x & 15;
  int d = threadIdx.x;
  int l0 = ch * CHL;
  int lim = min(CHL, L_ - l0);
  float Av[16];
#pragma unroll
  for (int q = 0; q < 4; q++) {
    float4 v = *(const float4*)(Aneg + d * 16 + q * 4);
    Av[q * 4] = v.x; Av[q * 4 + 1] = v.y; Av[q * 4 + 2] = v.z; Av[q * 4 + 3] = v.w;
  }
  float wdt = w_dt[d], bdt = b_dt[d];
  const __hip_bfloat16* xap = xa + ((size_t)b * L_ + l0) * DI_ + d;
  const float* bp = bcd + ((size_t)b * L_ + l0) * 64;
  float h[16], Pp[16];
#pragma unroll
  for (int n = 0; n < 16; n++) { h[n] = 0.f; Pp[n] = 1.f; }
  float xv = __bfloat162float(xap[0]);
  for (int j = 0; j < lim; j++) {
    int jn = (j + 1 < lim) ? (j + 1) : j;
    float xn = __bfloat162float(xap[(size_t)jn * DI_]);
    float dtraw = bp[j * 64 + 32];
    float Bn[16];
#pragma unroll
    for (int n = 0; n < 16; n++) Bn[n] = bp[j * 64 + n];
    float v = fmaf(dtraw, wdt, bdt);
    float dtv = (v > 20.f) ? v : __logf(1.f + __expf(v));
    float dtx = dtv * xv;
#pragma unroll
    for (int n = 0; n < 16; n++) {
      float dA = __expf(dtv * Av[n]);
      h[n] = fmaf(dA, h[n], dtx * Bn[n]);
      Pp[n] *= dA;
    }
    xv = xn;
  }
  size_t s = ((size_t)blockIdx.x * 384 + d) * 16;
#pragma unroll
  for (int q = 0; q < 4; q++) {
    *(float4*)(Pst + s + q * 4) = make_float4(Pp[q * 4], Pp[q * 4 + 1], Pp[q * 4 + 2], Pp[q * 4 + 3]);
    *(float4*)(Hst + s + q * 4) = make_float4(h[q * 4], h[q * 4 + 1], h[q * 4 + 2], h[q * 4 + 3]);
  }
}

// ---------------- scan phase 2: inline lookback + rescan + C-dot + D + silu(z) ----------------
__global__ __launch_bounds__(384) void k_scan2(const __hip_bfloat16* __restrict__ xa,
                                               const __hip_bfloat16* __restrict__ sz,
                                               const float* __restrict__ bcd,
                                               const float* __restrict__ Aneg,
                                               const float* __restrict__ D_ssm,
                                               const float* __restrict__ w_dt,
                                               const float* __restrict__ b_dt,
                                               const float* __restrict__ Pst,
                                               const float* __restrict__ Hst,
                                               __hip_bfloat16* __restrict__ y) {
  int b = blockIdx.x >> 4, ch = blockIdx.x & 15;
  int d = threadIdx.x;
  int l0 = ch * CHL;
  int lim = min(CHL, L_ - l0);
  float Av[16];
#pragma unroll
  for (int q = 0; q < 4; q++) {
    float4 v = *(const float4*)(Aneg + d * 16 + q * 4);
    Av[q * 4] = v.x; Av[q * 4 + 1] = v.y; Av[q * 4 + 2] = v.z; Av[q * 4 + 3] = v.w;
  }
  float Dv = D_ssm[d];
  float wdt = w_dt[d], bdt = b_dt[d];
  // lookback: h = combine of chunks 0..ch-1 (verified correct in r8)
  float h[16];
#pragma unroll
  for (int n = 0; n < 16; n++) h[n] = 0.f;
  for (int c = 0; c < ch; c++) {
    size_t o = ((size_t)(b * NCH + c) * 384 + d) * 16;
#pragma unroll
    for (int q = 0; q < 4; q++) {
      float4 P = *(const float4*)(Pst + o + q * 4);
      float4 H = *(const float4*)(Hst + o + q * 4);
      h[q * 4]     = fmaf(P.x, h[q * 4],     H.x);
      h[q * 4 + 1] = fmaf(P.y, h[q * 4 + 1], H.y);
      h[q * 4 + 2] = fmaf(P.z, h[q * 4 + 2], H.z);
      h[q * 4 + 3] = fmaf(P.w, h[q * 4 + 3], H.w);
    }
  }
  const __hip_bfloat16* xap = xa + ((size_t)b * L_ + l0) * DI_ + d;
  const __hip_bfloat16* szp = sz + ((size_t)b * L_ + l0) * DI_ + d;
  const float* bp = bcd + ((size_t)b * L_ + l0) * 64;
  __hip_bfloat16* yp = y + ((size_t)b * L_ + l0) * DI_ + d;
  float xv = __bfloat162float(xap[0]);
  float szv = __bfloat162float(szp[0]);
  for (int j = 0; j < lim; j++) {
    int jn = (j + 1 < lim) ? (j + 1) : j;
    float xn = __bfloat162float(xap[(size_t)jn * DI_]);
    float szn = __bfloat162float(szp[(size_t)jn * DI_]);
    float dtraw = bp[j * 64 + 32];
    float Bn[16], Cn[16];
#pragma unroll
    for (int n = 0; n < 16; n++) Bn[n] = bp[j * 64 + n];
#pragma unroll
    for (int n = 0; n < 16; n++) Cn[n] = bp[j * 64 + 16 + n];
    float v = fmaf(dtraw, wdt, bdt);
    float dtv = (v > 20.f) ? v : __logf(1.f + __expf(v));
    float dtx = dtv * xv;
    float acc = 0.f;
#pragma unroll
    for (int n = 0; n < 16; n++) {
      float dA = __expf(dtv * Av[n]);
      h[n] = fmaf(dA, h[n], dtx * Bn[n]);
      acc = fmaf(h[n], Cn[n], acc);
    }
    float yv = fmaf(xv, Dv, acc) * szv;
    yp[(size_t)j * DI_] = __float2bfloat16(yv);
    xv = xn; szv = szn;
  }
}

// ---------------- final LN(token 0) + cls head + reg head ----------------
__global__ __launch_bounds__(192) void k_head(const float* __restrict__ t,
                                              const float* __restrict__ fn_g,
                                              const float* __restrict__ fn_b,
                                              const float* __restrict__ cls_w,
                                              const float* __restrict__ cls_b,
                                              const float* __restrict__ rw1,
                                              const float* __restrict__ rb1,
                                              const float* __restrict__ rw2,
                                              const float* __restrict__ rb2,
                                              float* __restrict__ out) {
  __shared__ float red[8];
  __shared__ float stats[2];
  __shared__ float feat_s[192];
  __shared__ float h_s[96];
  int b = blockIdx.x, tid = threadIdx.x;
  float x = t[(size_t)b * L_ * D_ + tid];
  float s = x, q = x * x;
#pragma unroll
  for (int off = 1; off < 64; off <<= 1) {
    s += __shfl_xor(s, off, 64);
    q += __shfl_xor(q, off, 64);
  }
  int w = tid >> 6;
  if ((tid & 63) == 0) { red[w] = s; red[4 + w] = q; }
  __syncthreads();
  if (tid == 0) {
    float ss = red[0] + red[1] + red[2];
    float qq = red[4] + red[5] + red[6];
    float m = ss * (1.f / 192.f);
    stats[0] = m;
    stats[1] = rsqrtf(qq * (1.f / 192.f) - m * m + 1e-5f);
  }
  __syncthreads();
  float fv = (x - stats[0]) * stats[1] * fn_g[tid] + fn_b[tid];
  feat_s[tid] = fv;
  __syncthreads();
  if (tid < 96) {
    float a = rb1[tid];
    const float* wr = rw1 + (size_t)tid * 192;
    for (int k = 0; k < 192; k++) a = fmaf(feat_s[k], wr[k], a);
    h_s[tid] = 0.5f * a * (1.f + erff(a * 0.70710678118654752f));
  } else if (tid < 98) {
    int c = tid - 96;
    float a = cls_b[c];
    const float* wr = cls_w + (size_t)c * 192;
    for (int k = 0; k < 192; k++) a = fmaf(feat_s[k], wr[k], a);
    out[b * 2 + c] = a;
  }
  __syncthreads();
  if (tid == 0) {
    float a = rb2[0];
    for (int j = 0; j < 96; j++) a = fmaf(h_s[j], rw2[j], a);
    out[64 + b] = a;
  }
}

extern "C" void kernel_launch(void* const* d_in, const int* in_sizes, int n_in,
                              void* d_out, int out_size, void* d_ws, size_t ws_size,
                              hipStream_t stream) {
  const float* x       = (const float*)d_in[0];
  const float* patch_w = (const float*)d_in[1];
  const float* patch_b = (const float*)d_in[2];
  const float* cls_tok = (const float*)d_in[3];
  const float* pos     = (const float*)d_in[4];
  const float* ln_g    = (const float*)d_in[5];
  const float* ln_b    = (const float*)d_in[6];
  const float* w_in    = (const float*)d_in[7];
  const float* conv_w  = (const float*)d_in[8];
  const float* conv_b  = (const float*)d_in[9];
  const float* w_x     = (const float*)d_in[10];
  const float* w_dt    = (const float*)d_in[11];
  const float* b_dt    = (const float*)d_in[12];
  const float* A_log   = (const float*)d_in[13];
  const float* D_ssm   = (const float*)d_in[14];
  const float* w_out   = (const float*)d_in[15];
  const float* fn_g    = (const float*)d_in[16];
  const float* fn_b    = (const float*)d_in[17];
  const float* cls_w   = (const float*)d_in[18];
  const float* cls_b   = (const float*)d_in[19];
  const float* reg_w1  = (const float*)d_in[20];
  const float* reg_b1  = (const float*)d_in[21];
  const float* reg_w2  = (const float*)d_in[22];
  const float* reg_b2  = (const float*)d_in[23];
  float* out = (float*)d_out;

  float* ws = (float*)d_ws;
  // fp32 region
  float* t_buf = ws;                         // 1,210,368
  float* bcd   = t_buf + 1210368;            // 6336*64 = 405,504
  float* Pst   = bcd + 405504;               // 32*16*6144 = 3,145,728
  float* Hst   = Pst + 3145728;              // 3,145,728
  float* Aneg  = Hst + 3145728;              // 24,576
  // bf16 region
  __hip_bfloat16* xz_bf  = (__hip_bfloat16*)(Aneg + 24576);  // 6304*768 = 4,841,472
  __hip_bfloat16* Abuf   = xz_bf;            // alias: im2col output dead after patch gemm
  __hip_bfloat16* xa_bf  = xz_bf + 4841472;  // 6336*384 = 2,433,024
  __hip_bfloat16* sz_bf  = xa_bf + 2433024;  // 2,433,024
  __hip_bfloat16* y_bf   = sz_bf + 2433024;  // 2,433,024
  __hip_bfloat16* pw_bf  = y_bf + 2433024;   // 147,456
  __hip_bfloat16* win_bf = pw_bf + 147456;   // 589,824
  __hip_bfloat16* wout_bf = win_bf + 589824; // 294,912
  __hip_bfloat16* wx_bf  = wout_bf + 294912; // 98,304

  k_prep_im2col<<<23352, 256, 0, stream>>>(x, Abuf, patch_w, w_in, w_out, w_x,
                                           cls_tok, pos, A_log, pw_bf, win_bf,
                                           wout_bf, wx_bf, t_buf, Aneg);
  k_gemm_mfma<768, 2><<<dim3(98, 3), 256, 0, stream>>>(
      (const short*)Abuf, (const short*)pw_bf, t_buf, patch_b, pos, 6272);

  for (int i = 0; i < DEPTH_; i++) {
    k_gemm_in_ln<<<dim3(99, 12), 256, 0, stream>>>(
        t_buf, ln_g + i * D_, ln_b + i * D_,
        (const short*)(win_bf + (size_t)i * 147456), xz_bf);
    k_conv<<<788, 384, 0, stream>>>(xz_bf, conv_w + i * DI_ * DC_, conv_b + i * DI_,
                                    xa_bf, sz_bf);
    k_gemm_mfma<384, 3><<<dim3(99, 1), 256, 0, stream>>>(
        (const short*)xa_bf, (const short*)(wx_bf + (size_t)i * 24576), bcd,
        nullptr, nullptr, 6304);
    k_scan1<<<B_ * NCH, 384, 0, stream>>>(xa_bf, bcd, Aneg + i * 6144,
                                          w_dt + i * DI_, b_dt + i * DI_, Pst, Hst);
    k_scan2<<<B_ * NCH, 384, 0, stream>>>(xa_bf, sz_bf, bcd, Aneg + i * 6144,
                                          D_ssm + i * DI_, w_dt + i * DI_, b_dt + i * DI_,
                                          Pst, Hst, y_bf);
    k_gemm_out<<<dim3(99, 3), 256, 0, stream>>>(
        (const short*)y_bf, (const short*)(wout_bf + (size_t)i * 73728), t_buf);
  }
  k_head<<<32, 192, 0, stream>>>(t_buf, fn_g, fn_b, cls_w, cls_b, reg_w1, reg_b1,
                                 reg_w2, reg_b2, out);
}

// Round 10
// 536.301 us; speedup vs baseline: 1.4554x; 1.0532x over previous
//
#include <hip/hip_runtime.h>
#include <hip/hip_bf16.h>
#include <math.h>

// Problem constants
#define B_ 32
#define D_ 192
#define DEPTH_ 4
#define DI_ 384
#define DS_ 16
#define DC_ 4
#define P_ 16
#define IMG_ 224
#define N_ 196
#define L_ 197

// scan chunking
#define NCH 16
#define CHL 13   // 16*13 = 208 >= 197

typedef short s16x8 __attribute__((ext_vector_type(8)));
typedef float f32x16 __attribute__((ext_vector_type(16)));

__device__ __forceinline__ float sigmoidf_(float x) { return 1.f / (1.f + expf(-x)); }

// ---------------- merged im2col + prep ----------------
__global__ __launch_bounds__(256) void k_prep_im2col(
    const float* __restrict__ x, __hip_bfloat16* __restrict__ A,
    const float* __restrict__ patch_w, const float* __restrict__ w_in,
    const float* __restrict__ w_out, const float* __restrict__ w_x,
    const float* __restrict__ cls_tok, const float* __restrict__ pos,
    const float* __restrict__ A_log,
    __hip_bfloat16* __restrict__ pw, __hip_bfloat16* __restrict__ win,
    __hip_bfloat16* __restrict__ wout, __hip_bfloat16* __restrict__ wx,
    float* __restrict__ t, float* __restrict__ Aneg) {
  if (blockIdx.x < 18816) {
    int idx = blockIdx.x * 256 + threadIdx.x;  // 6272*768 exact
    int tok = idx / 768, f = idx - tok * 768;
    int b = tok / 196, p = tok - b * 196;
    int h = p / 14, w = p - h * 14;
    int c = f >> 8, i = (f >> 4) & 15, j = f & 15;
    float v = x[(((size_t)(b * 3 + c) * 224 + h * 16 + i) * 224 + w * 16 + j)];
    A[idx] = __float2bfloat16(v);
    return;
  }
  int idx = (blockIdx.x - 18816) * 256 + threadIdx.x;  // 1,161,216 exact
  if (idx < 147456) { pw[idx] = __float2bfloat16(patch_w[idx]); return; }
  idx -= 147456;
  if (idx < 589824) { win[idx] = __float2bfloat16(w_in[idx]); return; }
  idx -= 589824;
  if (idx < 294912) { wout[idx] = __float2bfloat16(w_out[idx]); return; }
  idx -= 294912;
  if (idx < 98304) {
    int li = idx / 24576;
    int r = (idx / 384) & 63;
    int c = idx % 384;
    wx[idx] = (r < 33) ? __float2bfloat16(w_x[(li * 33 + r) * 384 + c]) : __float2bfloat16(0.f);
    return;
  }
  idx -= 98304;
  if (idx < 6144) {
    int b = idx / 192, d = idx % 192;
    t[(size_t)b * L_ * D_ + d] = cls_tok[d] + pos[d];
    return;
  }
  idx -= 6144;
  Aneg[idx] = -expf(A_log[idx]);  // 24576
}

// ---------------- generic bf16 MFMA GEMM: C[M x N] = A[M x K] @ W[N x K]^T ----------------
// r7-verified shape: KC=96, STR=104 (26.6 KB LDS -> 6 blocks/CU). Do NOT grow LDS here.
// MODE 1: C fp32 (stride 192) += acc                 (t += y @ w_out^T)
// MODE 2: patch epilogue into t (fp32)
// MODE 3: C fp32 (stride 64) = acc                   (bcd = xa @ w_x_pad^T)
// MODE 4: C bf16 (stride 768) = acc                  (xz_bf = ln(t) @ w_in^T)
template <int KTOT, int MODE>
__global__ __launch_bounds__(256) void k_gemm_mfma(const short* __restrict__ A,
                                                   const short* __restrict__ Wb,
                                                   float* __restrict__ C,
                                                   const float* __restrict__ bias,
                                                   const float* __restrict__ pos,
                                                   int M) {
  constexpr int KC = 96;
  constexpr int STR = 104;
  __shared__ __align__(16) short Als[64 * STR];
  __shared__ __align__(16) short Bls[64 * STR];
  int m0 = blockIdx.x * 64, n0 = blockIdx.y * 64;
  int tid = threadIdx.x;
  int lane = tid & 63, wid = tid >> 6;
  int mw = (wid & 1) * 32, nw = (wid >> 1) * 32;
  int l31 = lane & 31, lh = lane >> 5;
  f32x16 acc;
#pragma unroll
  for (int i = 0; i < 16; i++) acc[i] = 0.f;
  for (int kc = 0; kc < KTOT; kc += KC) {
    __syncthreads();
#pragma unroll
    for (int i = 0; i < 3; i++) {
      int seg = tid + i * 256;
      int r = seg / 12, s = seg - r * 12;
      *(s16x8*)(Als + r * STR + s * 8) =
          *(const s16x8*)(A + (size_t)(m0 + r) * KTOT + kc + s * 8);
      *(s16x8*)(Bls + r * STR + s * 8) =
          *(const s16x8*)(Wb + (size_t)(n0 + r) * KTOT + kc + s * 8);
    }
    __syncthreads();
#pragma unroll
    for (int ks = 0; ks < KC / 16; ks++) {
      s16x8 af = *(const s16x8*)(Als + (mw + l31) * STR + ks * 16 + lh * 8);
      s16x8 bf = *(const s16x8*)(Bls + (nw + l31) * STR + ks * 16 + lh * 8);
      acc = __builtin_amdgcn_mfma_f32_32x32x16_bf16(af, bf, acc, 0, 0, 0);
    }
  }
  // epilogue: C/D layout col=lane&31, row=(reg&3)+8*(reg>>2)+4*(lane>>5)
  int gn = n0 + nw + l31;
#pragma unroll
  for (int i = 0; i < 16; i++) {
    int rowt = mw + (i & 3) + 8 * (i >> 2) + 4 * lh;
    int gm = m0 + rowt;
    float v = acc[i];
    if (MODE == 1) {
      if (gm < M) C[(size_t)gm * 192 + gn] += v;
    } else if (MODE == 3) {
      if (gm < M) C[(size_t)gm * 64 + gn] = v;
    } else if (MODE == 4) {
      if (gm < M) ((__hip_bfloat16*)C)[(size_t)gm * 768 + gn] = __float2bfloat16(v);
    } else {
      int b = gm / 196, p = gm - b * 196;
      C[((size_t)b * 197 + 1 + p) * 192 + gn] =
          v + bias[gn] + pos[(size_t)(1 + p) * 192 + gn];
    }
  }
}

// ---------------- LayerNorm, 4 tokens/block -> bf16 out (r7-verified) ----------------
__global__ __launch_bounds__(256) void k_ln_bf(const float* __restrict__ t,
                                               const float* __restrict__ g,
                                               const float* __restrict__ bb,
                                               __hip_bfloat16* __restrict__ o) {
  int tok = blockIdx.x * 4 + (threadIdx.x >> 6);
  int tid = threadIdx.x & 63;
  const float* xr = t + (size_t)tok * D_;
  float x0 = xr[tid], x1 = xr[tid + 64], x2 = xr[tid + 128];
  float s = x0 + x1 + x2;
  float q = x0 * x0 + x1 * x1 + x2 * x2;
#pragma unroll
  for (int off = 1; off < 64; off <<= 1) {
    s += __shfl_xor(s, off, 64);
    q += __shfl_xor(q, off, 64);
  }
  float m = s * (1.f / 192.f);
  float r = rsqrtf(q * (1.f / 192.f) - m * m + 1e-5f);
  __hip_bfloat16* orow = o + (size_t)tok * D_;
  orow[tid]       = __float2bfloat16((x0 - m) * r * g[tid]       + bb[tid]);
  orow[tid + 64]  = __float2bfloat16((x1 - m) * r * g[tid + 64]  + bb[tid + 64]);
  orow[tid + 128] = __float2bfloat16((x2 - m) * r * g[tid + 128] + bb[tid + 128]);
}

// ---------------- causal depthwise conv + silu: 8 tokens/block, LDS window (r7) ----------------
__global__ __launch_bounds__(384) void k_conv(const __hip_bfloat16* __restrict__ xz,
                                              const float* __restrict__ cw_,
                                              const float* __restrict__ cb,
                                              __hip_bfloat16* __restrict__ xa_bf,
                                              __hip_bfloat16* __restrict__ sz_bf) {
  __shared__ float xs[11][384];
  int r0 = blockIdx.x * 8;  // 788 blocks * 8 = 6304
  int d = threadIdx.x;
#pragma unroll
  for (int row = 0; row < 11; row++) {
    int gr = r0 - 3 + row;
    if (gr >= 0) xs[row][d] = __bfloat162float(xz[(size_t)gr * 768 + d]);
  }
  __syncthreads();
  float4 cw = *(const float4*)(cw_ + d * 4);
  float cbv = cb[d];
#pragma unroll
  for (int tk = 0; tk < 8; tk++) {
    int tok = r0 + tk;
    int l = tok % L_;
    float acc = fmaf(cw.w, xs[tk + 3][d], cbv);
    if (l >= 1) acc = fmaf(cw.z, xs[tk + 2][d], acc);
    if (l >= 2) acc = fmaf(cw.y, xs[tk + 1][d], acc);
    if (l >= 3) acc = fmaf(cw.x, xs[tk][d], acc);
    float xav = acc * sigmoidf_(acc);
    xa_bf[(size_t)tok * DI_ + d] = __float2bfloat16(xav);
    float z = __bfloat162float(xz[(size_t)tok * 768 + 384 + d]);
    sz_bf[(size_t)tok * DI_ + d] = __float2bfloat16(z * sigmoidf_(z));
  }
}

// ---------------- scan phase 1: chunk-local scan, store P (prod dA) and H_local ----------------
__global__ __launch_bounds__(384) void k_scan1(const __hip_bfloat16* __restrict__ xa,
                                               const float* __restrict__ bcd,
                                               const float* __restrict__ Aneg,
                                               const float* __restrict__ w_dt,
                                               const float* __restrict__ b_dt,
                                               float* __restrict__ Pst,
                                               float* __restrict__ Hst) {
  int b = blockIdx.x >> 4, ch = blockIdx.x & 15;
  int d = threadIdx.x;
  int l0 = ch * CHL;
  int lim = min(CHL, L_ - l0);
  float Av[16];
#pragma unroll
  for (int q = 0; q < 4; q++) {
    float4 v = *(const float4*)(Aneg + d * 16 + q * 4);
    Av[q * 4] = v.x; Av[q * 4 + 1] = v.y; Av[q * 4 + 2] = v.z; Av[q * 4 + 3] = v.w;
  }
  float wdt = w_dt[d], bdt = b_dt[d];
  const __hip_bfloat16* xap = xa + ((size_t)b * L_ + l0) * DI_ + d;
  const float* bp = bcd + ((size_t)b * L_ + l0) * 64;
  float h[16], Pp[16];
#pragma unroll
  for (int n = 0; n < 16; n++) { h[n] = 0.f; Pp[n] = 1.f; }
  float xv = __bfloat162float(xap[0]);
  for (int j = 0; j < lim; j++) {
    int jn = (j + 1 < lim) ? (j + 1) : j;
    float xn = __bfloat162float(xap[(size_t)jn * DI_]);
    float dtraw = bp[j * 64 + 32];
    float Bn[16];
#pragma unroll
    for (int n = 0; n < 16; n++) Bn[n] = bp[j * 64 + n];
    float v = fmaf(dtraw, wdt, bdt);
    float dtv = (v > 20.f) ? v : __logf(1.f + __expf(v));
    float dtx = dtv * xv;
#pragma unroll
    for (int n = 0; n < 16; n++) {
      float dA = __expf(dtv * Av[n]);
      h[n] = fmaf(dA, h[n], dtx * Bn[n]);
      Pp[n] *= dA;
    }
    xv = xn;
  }
  size_t s = ((size_t)blockIdx.x * 384 + d) * 16;
#pragma unroll
  for (int q = 0; q < 4; q++) {
    *(float4*)(Pst + s + q * 4) = make_float4(Pp[q * 4], Pp[q * 4 + 1], Pp[q * 4 + 2], Pp[q * 4 + 3]);
    *(float4*)(Hst + s + q * 4) = make_float4(h[q * 4], h[q * 4 + 1], h[q * 4 + 2], h[q * 4 + 3]);
  }
}

// ---------------- scan phase 2: inline lookback + rescan + C-dot + D + silu(z) ----------------
__global__ __launch_bounds__(384) void k_scan2(const __hip_bfloat16* __restrict__ xa,
                                               const __hip_bfloat16* __restrict__ sz,
                                               const float* __restrict__ bcd,
                                               const float* __restrict__ Aneg,
                                               const float* __restrict__ D_ssm,
                                               const float* __restrict__ w_dt,
                                               const float* __restrict__ b_dt,
                                               const float* __restrict__ Pst,
                                               const float* __restrict__ Hst,
                                               __hip_bfloat16* __restrict__ y) {
  int b = blockIdx.x >> 4, ch = blockIdx.x & 15;
  int d = threadIdx.x;
  int l0 = ch * CHL;
  int lim = min(CHL, L_ - l0);
  float Av[16];
#pragma unroll
  for (int q = 0; q < 4; q++) {
    float4 v = *(const float4*)(Aneg + d * 16 + q * 4);
    Av[q * 4] = v.x; Av[q * 4 + 1] = v.y; Av[q * 4 + 2] = v.z; Av[q * 4 + 3] = v.w;
  }
  float Dv = D_ssm[d];
  float wdt = w_dt[d], bdt = b_dt[d];
  // lookback: h = combine of chunks 0..ch-1 (algebra verified r8/r9)
  float h[16];
#pragma unroll
  for (int n = 0; n < 16; n++) h[n] = 0.f;
  for (int c = 0; c < ch; c++) {
    size_t o = ((size_t)(b * NCH + c) * 384 + d) * 16;
#pragma unroll
    for (int q = 0; q < 4; q++) {
      float4 P = *(const float4*)(Pst + o + q * 4);
      float4 H = *(const float4*)(Hst + o + q * 4);
      h[q * 4]     = fmaf(P.x, h[q * 4],     H.x);
      h[q * 4 + 1] = fmaf(P.y, h[q * 4 + 1], H.y);
      h[q * 4 + 2] = fmaf(P.z, h[q * 4 + 2], H.z);
      h[q * 4 + 3] = fmaf(P.w, h[q * 4 + 3], H.w);
    }
  }
  const __hip_bfloat16* xap = xa + ((size_t)b * L_ + l0) * DI_ + d;
  const __hip_bfloat16* szp = sz + ((size_t)b * L_ + l0) * DI_ + d;
  const float* bp = bcd + ((size_t)b * L_ + l0) * 64;
  __hip_bfloat16* yp = y + ((size_t)b * L_ + l0) * DI_ + d;
  float xv = __bfloat162float(xap[0]);
  float szv = __bfloat162float(szp[0]);
  for (int j = 0; j < lim; j++) {
    int jn = (j + 1 < lim) ? (j + 1) : j;
    float xn = __bfloat162float(xap[(size_t)jn * DI_]);
    float szn = __bfloat162float(szp[(size_t)jn * DI_]);
    float dtraw = bp[j * 64 + 32];
    float Bn[16], Cn[16];
#pragma unroll
    for (int n = 0; n < 16; n++) Bn[n] = bp[j * 64 + n];
#pragma unroll
    for (int n = 0; n < 16; n++) Cn[n] = bp[j * 64 + 16 + n];
    float v = fmaf(dtraw, wdt, bdt);
    float dtv = (v > 20.f) ? v : __logf(1.f + __expf(v));
    float dtx = dtv * xv;
    float acc = 0.f;
#pragma unroll
    for (int n = 0; n < 16; n++) {
      float dA = __expf(dtv * Av[n]);
      h[n] = fmaf(dA, h[n], dtx * Bn[n]);
      acc = fmaf(h[n], Cn[n], acc);
    }
    float yv = fmaf(xv, Dv, acc) * szv;
    yp[(size_t)j * DI_] = __float2bfloat16(yv);
    xv = xn; szv = szn;
  }
}

// ---------------- final LN(token 0) + cls head + reg head ----------------
__global__ __launch_bounds__(192) void k_head(const float* __restrict__ t,
                                              const float* __restrict__ fn_g,
                                              const float* __restrict__ fn_b,
                                              const float* __restrict__ cls_w,
                                              const float* __restrict__ cls_b,
                                              const float* __restrict__ rw1,
                                              const float* __restrict__ rb1,
                                              const float* __restrict__ rw2,
                                              const float* __restrict__ rb2,
                                              float* __restrict__ out) {
  __shared__ float red[8];
  __shared__ float stats[2];
  __shared__ float feat_s[192];
  __shared__ float h_s[96];
  int b = blockIdx.x, tid = threadIdx.x;
  float x = t[(size_t)b * L_ * D_ + tid];
  float s = x, q = x * x;
#pragma unroll
  for (int off = 1; off < 64; off <<= 1) {
    s += __shfl_xor(s, off, 64);
    q += __shfl_xor(q, off, 64);
  }
  int w = tid >> 6;
  if ((tid & 63) == 0) { red[w] = s; red[4 + w] = q; }
  __syncthreads();
  if (tid == 0) {
    float ss = red[0] + red[1] + red[2];
    float qq = red[4] + red[5] + red[6];
    float m = ss * (1.f / 192.f);
    stats[0] = m;
    stats[1] = rsqrtf(qq * (1.f / 192.f) - m * m + 1e-5f);
  }
  __syncthreads();
  float fv = (x - stats[0]) * stats[1] * fn_g[tid] + fn_b[tid];
  feat_s[tid] = fv;
  __syncthreads();
  if (tid < 96) {
    float a = rb1[tid];
    const float* wr = rw1 + (size_t)tid * 192;
    for (int k = 0; k < 192; k++) a = fmaf(feat_s[k], wr[k], a);
    h_s[tid] = 0.5f * a * (1.f + erff(a * 0.70710678118654752f));
  } else if (tid < 98) {
    int c = tid - 96;
    float a = cls_b[c];
    const float* wr = cls_w + (size_t)c * 192;
    for (int k = 0; k < 192; k++) a = fmaf(feat_s[k], wr[k], a);
    out[b * 2 + c] = a;
  }
  __syncthreads();
  if (tid == 0) {
    float a = rb2[0];
    for (int j = 0; j < 96; j++) a = fmaf(h_s[j], rw2[j], a);
    out[64 + b] = a;
  }
}

extern "C" void kernel_launch(void* const* d_in, const int* in_sizes, int n_in,
                              void* d_out, int out_size, void* d_ws, size_t ws_size,
                              hipStream_t stream) {
  const float* x       = (const float*)d_in[0];
  const float* patch_w = (const float*)d_in[1];
  const float* patch_b = (const float*)d_in[2];
  const float* cls_tok = (const float*)d_in[3];
  const float* pos     = (const float*)d_in[4];
  const float* ln_g    = (const float*)d_in[5];
  const float* ln_b    = (const float*)d_in[6];
  const float* w_in    = (const float*)d_in[7];
  const float* conv_w  = (const float*)d_in[8];
  const float* conv_b  = (const float*)d_in[9];
  const float* w_x     = (const float*)d_in[10];
  const float* w_dt    = (const float*)d_in[11];
  const float* b_dt    = (const float*)d_in[12];
  const float* A_log   = (const float*)d_in[13];
  const float* D_ssm   = (const float*)d_in[14];
  const float* w_out   = (const float*)d_in[15];
  const float* fn_g    = (const float*)d_in[16];
  const float* fn_b    = (const float*)d_in[17];
  const float* cls_w   = (const float*)d_in[18];
  const float* cls_b   = (const float*)d_in[19];
  const float* reg_w1  = (const float*)d_in[20];
  const float* reg_b1  = (const float*)d_in[21];
  const float* reg_w2  = (const float*)d_in[22];
  const float* reg_b2  = (const float*)d_in[23];
  float* out = (float*)d_out;

  float* ws = (float*)d_ws;
  // fp32 region
  float* t_buf = ws;                         // 1,210,368
  float* bcd   = t_buf + 1210368;            // 6336*64 = 405,504
  float* Pst   = bcd + 405504;               // 32*16*6144 = 3,145,728
  float* Hst   = Pst + 3145728;              // 3,145,728
  float* Aneg  = Hst + 3145728;              // 24,576
  // bf16 region
  __hip_bfloat16* xz_bf  = (__hip_bfloat16*)(Aneg + 24576);  // 6304*768 = 4,841,472
  __hip_bfloat16* Abuf   = xz_bf;            // alias: im2col output dead after patch gemm
  __hip_bfloat16* xa_bf  = xz_bf + 4841472;  // 6336*384 = 2,433,024
  __hip_bfloat16* sz_bf  = xa_bf + 2433024;  // 2,433,024
  __hip_bfloat16* xln_bf = sz_bf + 2433024;  // 6336*192 = 1,216,512
  __hip_bfloat16* y_bf   = xln_bf + 1216512; // 2,433,024
  __hip_bfloat16* pw_bf  = y_bf + 2433024;   // 147,456
  __hip_bfloat16* win_bf = pw_bf + 147456;   // 589,824
  __hip_bfloat16* wout_bf = win_bf + 589824; // 294,912
  __hip_bfloat16* wx_bf  = wout_bf + 294912; // 98,304

  k_prep_im2col<<<23352, 256, 0, stream>>>(x, Abuf, patch_w, w_in, w_out, w_x,
                                           cls_tok, pos, A_log, pw_bf, win_bf,
                                           wout_bf, wx_bf, t_buf, Aneg);
  k_gemm_mfma<768, 2><<<dim3(98, 3), 256, 0, stream>>>(
      (const short*)Abuf, (const short*)pw_bf, t_buf, patch_b, pos, 6272);

  for (int i = 0; i < DEPTH_; i++) {
    k_ln_bf<<<1576, 256, 0, stream>>>(t_buf, ln_g + i * D_, ln_b + i * D_, xln_bf);
    k_gemm_mfma<192, 4><<<dim3(99, 12), 256, 0, stream>>>(
        (const short*)xln_bf, (const short*)(win_bf + (size_t)i * 147456), (float*)xz_bf,
        nullptr, nullptr, 6304);
    k_conv<<<788, 384, 0, stream>>>(xz_bf, conv_w + i * DI_ * DC_, conv_b + i * DI_,
                                    xa_bf, sz_bf);
    k_gemm_mfma<384, 3><<<dim3(99, 1), 256, 0, stream>>>(
        (const short*)xa_bf, (const short*)(wx_bf + (size_t)i * 24576), bcd,
        nullptr, nullptr, 6304);
    k_scan1<<<B_ * NCH, 384, 0, stream>>>(xa_bf, bcd, Aneg + i * 6144,
                                          w_dt + i * DI_, b_dt + i * DI_, Pst, Hst);
    k_scan2<<<B_ * NCH, 384, 0, stream>>>(xa_bf, sz_bf, bcd, Aneg + i * 6144,
                                          D_ssm + i * DI_, w_dt + i * DI_, b_dt + i * DI_,
                                          Pst, Hst, y_bf);
    k_gemm_mfma<384, 1><<<dim3(99, 3), 256, 0, stream>>>(
        (const short*)y_bf, (const short*)(wout_bf + (size_t)i * 73728), t_buf,
        nullptr, nullptr, 6304);
  }
  k_head<<<32, 192, 0, stream>>>(t_buf, fn_g, fn_b, cls_w, cls_b, reg_w1, reg_b1,
                                 reg_w2, reg_b2, out);
}